// Round 16
// baseline (105.178 us; speedup 1.0000x reference)
//
#include <hip/hip_runtime.h>
#include <hip/hip_bf16.h>
#include <math.h>

#define B_ 2
#define S_ 2048
#define D_ 1024
#define H_ 16
#define HD_ 64
#define M_ (B_*S_)

typedef __attribute__((ext_vector_type(8))) short bf16x8;
typedef __attribute__((ext_vector_type(4))) float f32x4;

#define MFMA16(a,b,c) __builtin_amdgcn_mfma_f32_16x16x32_bf16(a,b,c,0,0,0)
#define INFF __builtin_inff()
#define LOG2E 1.44269504088896340736f
#define EXP2F(x) __builtin_amdgcn_exp2f(x)

static __device__ __forceinline__ unsigned short f2bf_bits(float f) {
    unsigned int u = __float_as_uint(f);
    unsigned int r = (u + 0x7fffu + ((u >> 16) & 1u)) >> 16;
    return (unsigned short)r;
}

// pack 2 f32 -> 2 bf16 in one dword (lo=a, hi=b), RNE
static __device__ __forceinline__ unsigned cvt_pk_bf16(float a, float b) {
    unsigned r;
    asm("v_cvt_pk_bf16_f32 %0, %1, %2" : "=v"(r) : "v"(a), "v"(b));
    return r;
}

// async global->LDS, 16B per lane; LDS dest = wave-uniform base + lane*16
static __device__ __forceinline__ void gload16(const unsigned short* g, unsigned short* l) {
    __builtin_amdgcn_global_load_lds(
        (const __attribute__((address_space(1))) unsigned int*)(g),
        (__attribute__((address_space(3))) unsigned int*)(l),
        16, 0, 0);
}

#define BARR do { \
    __builtin_amdgcn_sched_barrier(0); \
    __builtin_amdgcn_s_barrier(); \
    __builtin_amdgcn_sched_barrier(0); \
} while (0)
#define LGK0 do { \
    asm volatile("s_waitcnt lgkmcnt(0)" ::: "memory"); \
    __builtin_amdgcn_sched_barrier(0); \
} while (0)
#define LGK8 do { \
    asm volatile("s_waitcnt lgkmcnt(8)" ::: "memory"); \
    __builtin_amdgcn_sched_barrier(0); \
} while (0)
#define VM0 do { \
    asm volatile("s_waitcnt vmcnt(0)" ::: "memory"); \
    __builtin_amdgcn_sched_barrier(0); \
} while (0)
#define VM4 do { \
    asm volatile("s_waitcnt vmcnt(4)" ::: "memory"); \
    __builtin_amdgcn_sched_barrier(0); \
} while (0)
#define VM6 do { \
    asm volatile("s_waitcnt vmcnt(6)" ::: "memory"); \
    __builtin_amdgcn_sched_barrier(0); \
} while (0)

// ---------------- prep kernels ----------------
__global__ __launch_bounds__(256) void convert_x_kernel(
    const float* __restrict__ x, unsigned short* __restrict__ o) {
    size_t i = (size_t)blockIdx.x * 256 + threadIdx.x;   // 1M float4s
    float4 v = reinterpret_cast<const float4*>(x)[i];
    ushort4 u;
    u.x = f2bf_bits(v.x); u.y = f2bf_bits(v.y);
    u.z = f2bf_bits(v.z); u.w = f2bf_bits(v.w);
    reinterpret_cast<ushort4*>(o)[i] = u;
}

// W [k][n] f32 -> WT [n][k] bf16 (tiled transpose)
__global__ __launch_bounds__(256) void convw_kernel(
    const float* __restrict__ W0, const float* __restrict__ W1,
    const float* __restrict__ W2, const float* __restrict__ W3,
    unsigned short* __restrict__ OT) {
    __shared__ float t[32][33];
    const float* W = (blockIdx.z == 0) ? W0 : (blockIdx.z == 1) ? W1
                    : (blockIdx.z == 2) ? W2 : W3;
    unsigned short* O = OT + (size_t)blockIdx.z * D_ * D_;
    int tx = threadIdx.x & 31, ty = threadIdx.x >> 5;
    int kb = blockIdx.y * 32, nb = blockIdx.x * 32;
#pragma unroll
    for (int i = 0; i < 4; i++)
        t[ty + 8*i][tx] = W[(size_t)(kb + ty + 8*i) * D_ + nb + tx];
    __syncthreads();
#pragma unroll
    for (int i = 0; i < 4; i++) {
        int n = nb + ty + 8*i, k = kb + tx;
        O[(size_t)n * D_ + k] = f2bf_bits(t[tx][ty + 8*i]);
    }
}

// ---------------- QKV GEMM: 256x256 tile, 8 waves, 8-phase (r9) ------------
__global__ __launch_bounds__(512, 2) void gemm_qkv256(
    const unsigned short* __restrict__ A,
    const unsigned short* __restrict__ BT,
    unsigned short* __restrict__ outp)
{
    __shared__ union {
        struct { unsigned short A[2][2][8192]; unsigned short B[2][2][8192]; } s;
        unsigned short vt[256][136];
    } sm;
    const int tid = threadIdx.x, lane = tid & 63, wid = tid >> 6;
    const int lrow = lane & 15, lk8 = lane >> 4, orow = lk8 * 4;
    const int wmo = (wid >> 2) * 64;
    const int wno = (wid & 3) * 32;
    const int m0 = blockIdx.x * 256, n0 = blockIdx.y * 256;

    const int srow = lane >> 3, sgr = lane & 7;
    const unsigned sgo = (unsigned)(wid * 8 + srow) * 1024u
                       + (unsigned)((sgr ^ srow) << 3);
    const unsigned short* Ag = A  + (unsigned)m0 * 1024u + sgo;
    const unsigned short* Bg = BT + (unsigned)n0 * 1024u + sgo;
    const int ldsrb = wid * 512;

    const int sw0 = ((lk8 ^ (lrow & 7)) << 3);
    const int sw1 = (((4 | lk8) ^ (lrow & 7)) << 3);
    int ar[4], br[2];
#pragma unroll
    for (int f = 0; f < 4; f++) ar[f] = (wmo + f * 16 + lrow) * 64;
#pragma unroll
    for (int g = 0; g < 2; g++) br[g] = (wno + g * 16 + lrow) * 64;

    f32x4 acc[8][4] = {};
    bf16x8 af[4][2], bf0[2][2], bf1[2][2];

    auto stA = [&](int par, int mh, unsigned k) {
        unsigned short* d = &sm.s.A[par][mh][ldsrb];
        const unsigned short* g = Ag + (unsigned)mh * 131072u + k;
        gload16(g, d);
        gload16(g + 65536u, d + 4096);
    };
    auto stB = [&](int par, int nh, unsigned k) {
        unsigned short* d = &sm.s.B[par][nh][ldsrb];
        const unsigned short* g = Bg + (unsigned)nh * 131072u + k;
        gload16(g, d);
        gload16(g + 65536u, d + 4096);
    };
    auto lda = [&](int par, int mh) {
        const unsigned short* p = &sm.s.A[par][mh][0];
#pragma unroll
        for (int f = 0; f < 4; f++) {
            af[f][0] = *reinterpret_cast<const bf16x8*>(p + ar[f] + sw0);
            af[f][1] = *reinterpret_cast<const bf16x8*>(p + ar[f] + sw1);
        }
    };
    auto ldb0 = [&](int par, int nh) {
        const unsigned short* p = &sm.s.B[par][nh][0];
#pragma unroll
        for (int g = 0; g < 2; g++) {
            bf0[g][0] = *reinterpret_cast<const bf16x8*>(p + br[g] + sw0);
            bf0[g][1] = *reinterpret_cast<const bf16x8*>(p + br[g] + sw1);
        }
    };
    auto ldb1 = [&](int par, int nh) {
        const unsigned short* p = &sm.s.B[par][nh][0];
#pragma unroll
        for (int g = 0; g < 2; g++) {
            bf1[g][0] = *reinterpret_cast<const bf16x8*>(p + br[g] + sw0);
            bf1[g][1] = *reinterpret_cast<const bf16x8*>(p + br[g] + sw1);
        }
    };
    auto MMA0 = [&](int mh) {
        __builtin_amdgcn_s_setprio(1);
#pragma unroll
        for (int f = 0; f < 4; f++)
#pragma unroll
            for (int g = 0; g < 2; g++)
#pragma unroll
                for (int ks = 0; ks < 2; ks++)
                    acc[mh*4+f][g] = MFMA16(af[f][ks], bf0[g][ks], acc[mh*4+f][g]);
        __builtin_amdgcn_s_setprio(0);
    };
    auto MMA1 = [&](int mh) {
        __builtin_amdgcn_s_setprio(1);
#pragma unroll
        for (int f = 0; f < 4; f++)
#pragma unroll
            for (int g = 0; g < 2; g++)
#pragma unroll
                for (int ks = 0; ks < 2; ks++)
                    acc[mh*4+f][2+g] = MFMA16(af[f][ks], bf1[g][ks], acc[mh*4+f][2+g]);
        __builtin_amdgcn_s_setprio(0);
    };

    stA(0, 0, 0);  stB(0, 0, 0);  stB(0, 1, 0);  stA(0, 1, 0);
    stA(1, 0, 64); stB(1, 0, 64); stB(1, 1, 64);
    VM6; BARR;

#pragma unroll 1
    for (int i = 0; i < 8; i++) {
        const unsigned kA1 = (unsigned)(2*i + 1) * 64u;
        const unsigned k2  = (unsigned)((2*i + 2) & 15) * 64u;
        const unsigned k3  = (unsigned)((2*i + 3) & 15) * 64u;
        lda(0, 0); ldb0(0, 0); stA(1, 1, kA1);
        LGK8; BARR; LGK0; MMA0(0); BARR;
        ldb1(0, 1); stA(0, 0, k2);
        BARR; LGK0; MMA1(0); BARR;
        lda(0, 1); stB(0, 0, k2);
        BARR; LGK0; MMA1(1); BARR;
        stB(0, 1, k2);
        VM6; BARR; MMA0(1); BARR;
        lda(1, 0); ldb0(1, 0); stA(0, 1, k2);
        LGK8; BARR; LGK0; MMA0(0); BARR;
        ldb1(1, 1); stA(1, 0, k3);
        BARR; LGK0; MMA1(0); BARR;
        lda(1, 1); stB(1, 0, k3);
        BARR; LGK0; MMA1(1); BARR;
        stB(1, 1, k3);
        VM6; BARR; MMA0(1); BARR;
    }

    asm volatile("s_waitcnt vmcnt(0)" ::: "memory");
    __builtin_amdgcn_sched_barrier(0);
    __builtin_amdgcn_s_barrier();

    const int which = n0 >> 10;
    const int nl0 = n0 & 1023;
    const int bq = m0 >> 11;
    unsigned short* obase = outp + (size_t)which * 4194304;

    if (which < 2) {
        const float scale = (which == 0) ? (0.125f * LOG2E) : 1.0f;
#pragma unroll
        for (int fi = 0; fi < 8; fi++)
#pragma unroll
            for (int g = 0; g < 4; g++)
#pragma unroll
                for (int r = 0; r < 4; r++) {
                    int m = m0 + (fi >> 2) * 128 + wmo + (fi & 3) * 16 + orow + r;
                    int n = nl0 + (g >> 1) * 128 + wno + (g & 1) * 16 + lrow;
                    int s = m & 2047;
                    obase[(((size_t)(bq * 16 + (n >> 6)) * 2048 + s) << 6) + (n & 63)]
                        = f2bf_bits(acc[fi][g][r] * scale);
                }
    } else {
#pragma unroll
        for (int qm = 0; qm < 2; qm++) {
#pragma unroll
            for (int f = 0; f < 4; f++)
#pragma unroll
                for (int g = 0; g < 4; g++) {
                    const int ml = wmo + f * 16 + orow;
                    const int nc = (g >> 1) * 128 + wno + (g & 1) * 16 + lrow;
                    uint2 w;
                    w.x = cvt_pk_bf16(acc[qm*4+f][g][0], acc[qm*4+f][g][1]);
                    w.y = cvt_pk_bf16(acc[qm*4+f][g][2], acc[qm*4+f][g][3]);
                    *reinterpret_cast<uint2*>(&sm.vt[nc][ml]) = w;
                }
            __syncthreads();
            {
                const int row = tid >> 1, c0 = (tid & 1) * 64;
                unsigned short* dst = obase +
                    ((size_t)(bq * 1024) + nl0 + row) * 2048 +
                    (m0 & 2047) + qm * 128 + c0;
#pragma unroll
                for (int j = 0; j < 64; j += 8)
                    *reinterpret_cast<bf16x8*>(dst + j) =
                        *reinterpret_cast<const bf16x8*>(&sm.vt[row][c0 + j]);
            }
            __syncthreads();
        }
    }
}

// ---------------- proj GEMM (128x64 tiles — round-9 config) ----------------
template<int BN, int MODE>
__global__ __launch_bounds__(256) void gemm_gl(
    const unsigned short* __restrict__ A,
    const unsigned short* __restrict__ BT,
    void* __restrict__ outp,
    const float* __restrict__ bias)
{
    constexpr int K = 1024;
    constexpr int NF = (BN == 128) ? 4 : 2;
    __shared__ struct { unsigned short As[128][64]; unsigned short Bs[BN][64]; } sm;
    const int m0 = blockIdx.x * 128;
    const int n0 = blockIdx.y * BN;
    const int tid = threadIdx.x, lane = tid & 63, wid = tid >> 6;
    const int wm = (wid >> 1) * 64;
    const int wn = (wid & 1) * (BN / 2);
    const int lrow = lane & 15, lk8 = lane >> 4, orow = lk8 * 4;
    f32x4 acc[4][NF] = {};

    for (int k0 = 0; k0 < K; k0 += 64) {
#pragma unroll
        for (int i = 0; i < 4; i++) {
            const int rbase = wid * 32 + i * 8;
            const int rl = rbase + (lane >> 3);
            const int sc = ((lane & 7) ^ (rl & 7)) << 3;
            gload16(A + (size_t)(m0 + rl) * K + k0 + sc, &sm.As[rbase][0]);
        }
#pragma unroll
        for (int i = 0; i < BN / 32; i++) {
            const int rbase = wid * (BN / 4) + i * 8;
            const int rl = rbase + (lane >> 3);
            const int sc = ((lane & 7) ^ (rl & 7)) << 3;
            gload16(BT + (size_t)(n0 + rl) * K + k0 + sc, &sm.Bs[rbase][0]);
        }
        __syncthreads();
#pragma unroll
        for (int ks = 0; ks < 2; ks++) {
            bf16x8 af[4], bfr[NF];
#pragma unroll
            for (int f = 0; f < 4; f++) {
                const int row = wm + f * 16 + lrow;
                const int p = (ks * 4 + lk8) ^ (row & 7);
                af[f] = *reinterpret_cast<const bf16x8*>(&sm.As[row][p * 8]);
            }
#pragma unroll
            for (int f = 0; f < NF; f++) {
                const int row = wn + f * 16 + lrow;
                const int p = (ks * 4 + lk8) ^ (row & 7);
                bfr[f] = *reinterpret_cast<const bf16x8*>(&sm.Bs[row][p * 8]);
            }
            __builtin_amdgcn_s_setprio(1);
#pragma unroll
            for (int mf = 0; mf < 4; mf++)
#pragma unroll
                for (int nf = 0; nf < NF; nf++)
                    acc[mf][nf] = MFMA16(af[mf], bfr[nf], acc[mf][nf]);
            __builtin_amdgcn_s_setprio(0);
        }
        __syncthreads();
    }

    float* o = (float*)outp;
#pragma unroll
    for (int mf = 0; mf < 4; mf++)
#pragma unroll
        for (int nf = 0; nf < NF; nf++)
#pragma unroll
            for (int r = 0; r < 4; r++) {
                int m = m0 + wm + mf*16 + orow + r;
                int n = n0 + wn + nf*16 + lrow;
                o[(size_t)m * 1024 + n] = acc[mf][nf][r] + bias[n];
            }
}

// ---------------- flash attention: paired q-tiles, shared KV staging -------
// 512 blocks = 16 pairs x 32 bh. Block p runs q-tiles A=p and B=31-p in the
// SAME kv loop: staged K/V tiles and their ds_reads are shared (A inactive
// for kvb>p). 3 rotating buffers + counted vmcnt publish (r14/r15). In-reg
// P via cvt_pk + permlane swaps (r15). All 512 blocks co-resident (2/CU).
__global__ __launch_bounds__(256, 2) void attn_kernel(
    const unsigned short* __restrict__ Q,   // [bh][s][64]
    const unsigned short* __restrict__ Kb,  // [bh][s][64]
    const unsigned short* __restrict__ VT,  // [bh][64][s]
    unsigned short* __restrict__ ctx)       // [b][s][h*64+hd]
{
    __shared__ unsigned short Ks[3][64][64];
    __shared__ unsigned short Vs[3][64][64];
    const int fid = blockIdx.x;                   // 512
    const int xcd = fid & 7, t = fid >> 3;        // t: 0..63
    const int bh = xcd | ((t & 3) << 3);          // 4 bh per XCD
    const int p  = t >> 2;                        // 0..15 (heaviest first)
    const int qtA = p, qtB = 31 - p;
    const int lane = threadIdx.x & 63, wid = threadIdx.x >> 6;
    const int lrow = lane & 15, lk8 = lane >> 4, orow = lk8 * 4;
    const unsigned short* Qp = Q  + (size_t)bh * (S_ * 64);
    const unsigned short* Kp = Kb + (size_t)bh * (S_ * 64);
    const unsigned short* Vp = VT + (size_t)bh * (64 * S_);
    const int b = bh >> 4, h = bh & 15;
    const int q0A = qtA * 64 + wid * 16;
    const int q0B = qtB * 64 + wid * 16;
    const int nb = qtB + 1;

    auto stage = [&](int buf, int kv0) {
#pragma unroll
        for (int i = 0; i < 2; i++) {
            const int rbase = wid * 16 + 8 * i;          // wave-uniform
            const int rl = rbase + (lane >> 3);          // per-lane row
            const int sc = (((lane & 7) ^ (rl & 7)) << 3);
            gload16(Kp + (size_t)(kv0 + rl) * 64 + sc, &Ks[buf][rbase][0]);
            gload16(Vp + (size_t)rl * S_ + kv0 + sc, &Vs[buf][rbase][0]);
        }
    };

    stage(0, 0);
    stage(1, 64);    // rows always in-bounds (S=2048); unused if nb<2

    bf16x8 qfA[2], qfB[2];
#pragma unroll
    for (int kt = 0; kt < 2; kt++) {
        qfA[kt] = *reinterpret_cast<const bf16x8*>(
            Qp + (size_t)(q0A + lrow) * 64 + kt*32 + lk8*8);
        qfB[kt] = *reinterpret_cast<const bf16x8*>(
            Qp + (size_t)(q0B + lrow) * 64 + kt*32 + lk8*8);
    }

    f32x4 accA[4] = {}, accB[4] = {};
    float lrA = 0.f, lrB = 0.f;

    VM4;    // stage(0) landed; stage(1) still in flight
    BARR;

    int cur = 0, n2 = 2;
#pragma unroll 1
    for (int kvb = 0; kvb < nb; kvb++) {
        if (kvb + 2 < nb) stage(n2, (kvb + 2) * 64);
        const bool aAct = (kvb <= qtA);

        // ---- S^T = K·Q^T, K frags SHARED between tiles A and B ----
        f32x4 sA[4] = {}, sB[4] = {};
        __builtin_amdgcn_s_setprio(1);
        if (aAct) {
#pragma unroll
            for (int kt = 0; kt < 2; kt++)
#pragma unroll
                for (int nf = 0; nf < 4; nf++) {
                    const int row = nf * 16 + lrow;
                    const int g = ((kt << 2) | lk8) ^ (row & 7);
                    bf16x8 kf = *reinterpret_cast<const bf16x8*>(&Ks[cur][row][g << 3]);
                    sB[nf] = MFMA16(kf, qfB[kt], sB[nf]);
                    sA[nf] = MFMA16(kf, qfA[kt], sA[nf]);
                }
        } else {
#pragma unroll
            for (int kt = 0; kt < 2; kt++)
#pragma unroll
                for (int nf = 0; nf < 4; nf++) {
                    const int row = nf * 16 + lrow;
                    const int g = ((kt << 2) | lk8) ^ (row & 7);
                    bf16x8 kf = *reinterpret_cast<const bf16x8*>(&Ks[cur][row][g << 3]);
                    sB[nf] = MFMA16(kf, qfB[kt], sB[nf]);
                }
        }
        __builtin_amdgcn_s_setprio(0);

        // ---- causal masks (diagonal tiles only) ----
        if (kvb == qtB) {
#pragma unroll
            for (int nf = 0; nf < 4; nf++)
#pragma unroll
                for (int r = 0; r < 4; r++)
                    if (nf*16 + orow + r > wid*16 + lrow) sB[nf][r] = -INFF;
        }
        if (aAct && kvb == qtA) {
#pragma unroll
            for (int nf = 0; nf < 4; nf++)
#pragma unroll
                for (int r = 0; r < 4; r++)
                    if (nf*16 + orow + r > wid*16 + lrow) sA[nf][r] = -INFF;
        }

        // ---- fixed-max softmax (exp2, log2e pre-folded) + in-reg P ----
        bf16x8 pfB[2], pfA[2];
        {
            float ps[4];
#pragma unroll
            for (int nf = 0; nf < 4; nf++) {
#pragma unroll
                for (int r = 0; r < 4; r++)
                    sB[nf][r] = EXP2F(sB[nf][r]);
                ps[nf] = (sB[nf][0] + sB[nf][1]) + (sB[nf][2] + sB[nf][3]);
            }
            lrB += (ps[0] + ps[1]) + (ps[2] + ps[3]);
#pragma unroll
            for (int kt = 0; kt < 2; kt++) {
                unsigned a0 = cvt_pk_bf16(sB[2*kt][0],   sB[2*kt][1]);
                unsigned a1 = cvt_pk_bf16(sB[2*kt][2],   sB[2*kt][3]);
                unsigned b0 = cvt_pk_bf16(sB[2*kt+1][0], sB[2*kt+1][1]);
                unsigned b1 = cvt_pk_bf16(sB[2*kt+1][2], sB[2*kt+1][3]);
                asm("v_permlane32_swap_b32 %0, %1" : "+v"(a0), "+v"(b0));
                asm("v_permlane16_swap_b32 %0, %1" : "+v"(a0), "+v"(b0));
                asm("v_permlane32_swap_b32 %0, %1" : "+v"(a1), "+v"(b1));
                asm("v_permlane16_swap_b32 %0, %1" : "+v"(a1), "+v"(b1));
                union { unsigned u[4]; bf16x8 v; } pk;
                pk.u[0] = a0; pk.u[1] = a1; pk.u[2] = b0; pk.u[3] = b1;
                pfB[kt] = pk.v;
            }
        }
        if (aAct) {
            float ps[4];
#pragma unroll
            for (int nf = 0; nf < 4; nf++) {
#pragma unroll
                for (int r = 0; r < 4; r++)
                    sA[nf][r] = EXP2F(sA[nf][r]);
                ps[nf] = (sA[nf][0] + sA[nf][1]) + (sA[nf][2] + sA[nf][3]);
            }
            lrA += (ps[0] + ps[1]) + (ps[2] + ps[3]);
#pragma unroll
            for (int kt = 0; kt < 2; kt++) {
                unsigned a0 = cvt_pk_bf16(sA[2*kt][0],   sA[2*kt][1]);
                unsigned a1 = cvt_pk_bf16(sA[2*kt][2],   sA[2*kt][3]);
                unsigned b0 = cvt_pk_bf16(sA[2*kt+1][0], sA[2*kt+1][1]);
                unsigned b1 = cvt_pk_bf16(sA[2*kt+1][2], sA[2*kt+1][3]);
                asm("v_permlane32_swap_b32 %0, %1" : "+v"(a0), "+v"(b0));
                asm("v_permlane16_swap_b32 %0, %1" : "+v"(a0), "+v"(b0));
                asm("v_permlane32_swap_b32 %0, %1" : "+v"(a1), "+v"(b1));
                asm("v_permlane16_swap_b32 %0, %1" : "+v"(a1), "+v"(b1));
                union { unsigned u[4]; bf16x8 v; } pk;
                pk.u[0] = a0; pk.u[1] = a1; pk.u[2] = b0; pk.u[3] = b1;
                pfA[kt] = pk.v;
            }
        }

        // ---- PV: V frags SHARED between tiles ----
        __builtin_amdgcn_s_setprio(1);
        if (aAct) {
#pragma unroll
            for (int kt = 0; kt < 2; kt++)
#pragma unroll
                for (int nf = 0; nf < 4; nf++) {
                    const int row = nf * 16 + lrow;      // hd row of VT
                    const int g = ((kt << 2) | lk8) ^ (row & 7);
                    bf16x8 vf = *reinterpret_cast<const bf16x8*>(&Vs[cur][row][g << 3]);
                    accB[nf] = MFMA16(pfB[kt], vf, accB[nf]);
                    accA[nf] = MFMA16(pfA[kt], vf, accA[nf]);
                }
        } else {
#pragma unroll
            for (int kt = 0; kt < 2; kt++)
#pragma unroll
                for (int nf = 0; nf < 4; nf++) {
                    const int row = nf * 16 + lrow;
                    const int g = ((kt << 2) | lk8) ^ (row & 7);
                    bf16x8 vf = *reinterpret_cast<const bf16x8*>(&Vs[cur][row][g << 3]);
                    accB[nf] = MFMA16(pfB[kt], vf, accB[nf]);
                }
        }
        __builtin_amdgcn_s_setprio(0);

        // ---- counted publish: keep newest stage in flight (T4) ----
        if (kvb + 1 < nb) {
            if (kvb + 2 < nb) { VM4; } else { VM0; }
            BARR;
        }
        cur = (cur == 2) ? 0 : cur + 1;
        n2  = (n2  == 2) ? 0 : n2  + 1;
    }

    asm volatile("s_waitcnt vmcnt(0)" ::: "memory");

    // ---- epilogue: per-tile denominator reduce + write ----
    lrA += __shfl_xor(lrA, 16);
    lrA += __shfl_xor(lrA, 32);
    lrB += __shfl_xor(lrB, 16);
    lrB += __shfl_xor(lrB, 32);
    const float invA = 1.0f / lrA;
    const float invB = 1.0f / lrB;
#pragma unroll
    for (int r = 0; r < 4; r++) {
        const float liA = __shfl(invA, (lane & 48) + orow + r);
        const float liB = __shfl(invB, (lane & 48) + orow + r);
#pragma unroll
        for (int nf = 0; nf < 4; nf++) {
            const int col = h * 64 + nf * 16 + lrow;
            ctx[((size_t)(b * S_ + q0A + orow + r)) * D_ + col]
                = f2bf_bits(accA[nf][r] * liA);
            ctx[((size_t)(b * S_ + q0B + orow + r)) * D_ + col]
                = f2bf_bits(accB[nf][r] * liB);
        }
    }
}

// ---------------- launch ----------------
extern "C" void kernel_launch(void* const* d_in, const int* in_sizes, int n_in,
                              void* d_out, int out_size, void* d_ws, size_t ws_size,
                              hipStream_t stream) {
    const float* x  = (const float*)d_in[0];
    const float* Wq = (const float*)d_in[1];
    const float* Wk = (const float*)d_in[2];
    const float* Wv = (const float*)d_in[3];
    const float* Wo = (const float*)d_in[4];
    const float* bo = (const float*)d_in[5];
    float* out = (float*)d_out;

    char* ws = (char*)d_ws;
    unsigned short* xb  = (unsigned short*)(ws);                 // 8 MiB
    unsigned short* WT  = (unsigned short*)(ws + 8388608);       // 4 x 2 MiB
    unsigned short* QKV = (unsigned short*)(ws + 16777216);      // 24 MiB: Q,K,VT
    unsigned short* ctx = (unsigned short*)(ws + 41943040);      // 8 MiB

    unsigned short* Qb  = QKV;
    unsigned short* Kb  = QKV + 4194304;
    unsigned short* VTb = QKV + 8388608;

    convert_x_kernel<<<dim3(4096), dim3(256), 0, stream>>>(x, xb);
    convw_kernel<<<dim3(32, 32, 4), dim3(256), 0, stream>>>(Wq, Wk, Wv, Wo, WT);

    // fused QKV projection: 256x256 tiles, N=3072
    gemm_qkv256<<<dim3(16, 12), dim3(512), 0, stream>>>(xb, WT, QKV);

    attn_kernel<<<dim3(512), dim3(256), 0, stream>>>(Qb, Kb, VTb, ctx);

    // output projection: N=1024, 128x64 tiles for 512 blocks
    gemm_gl<64, 1><<<dim3(32, 16), dim3(256), 0, stream>>>(
        ctx, WT + 3145728, (void*)out, bo);
}

// Round 17
// 102.544 us; speedup vs baseline: 1.0257x; 1.0257x over previous
//
#include <hip/hip_runtime.h>
#include <hip/hip_bf16.h>
#include <math.h>

#define B_ 2
#define S_ 2048
#define D_ 1024
#define H_ 16
#define HD_ 64
#define M_ (B_*S_)

typedef __attribute__((ext_vector_type(8))) short bf16x8;
typedef __attribute__((ext_vector_type(4))) float f32x4;

#define MFMA16(a,b,c) __builtin_amdgcn_mfma_f32_16x16x32_bf16(a,b,c,0,0,0)
#define INFF __builtin_inff()
#define LOG2E 1.44269504088896340736f
#define EXP2F(x) __builtin_amdgcn_exp2f(x)

static __device__ __forceinline__ unsigned short f2bf_bits(float f) {
    unsigned int u = __float_as_uint(f);
    unsigned int r = (u + 0x7fffu + ((u >> 16) & 1u)) >> 16;
    return (unsigned short)r;
}

// pack 2 f32 -> 2 bf16 in one dword (lo=a, hi=b), RNE
static __device__ __forceinline__ unsigned cvt_pk_bf16(float a, float b) {
    unsigned r;
    asm("v_cvt_pk_bf16_f32 %0, %1, %2" : "=v"(r) : "v"(a), "v"(b));
    return r;
}

// async global->LDS, 16B per lane; LDS dest = wave-uniform base + lane*16
static __device__ __forceinline__ void gload16(const unsigned short* g, unsigned short* l) {
    __builtin_amdgcn_global_load_lds(
        (const __attribute__((address_space(1))) unsigned int*)(g),
        (__attribute__((address_space(3))) unsigned int*)(l),
        16, 0, 0);
}

#define BARR do { \
    __builtin_amdgcn_sched_barrier(0); \
    __builtin_amdgcn_s_barrier(); \
    __builtin_amdgcn_sched_barrier(0); \
} while (0)
#define LGK0 do { \
    asm volatile("s_waitcnt lgkmcnt(0)" ::: "memory"); \
    __builtin_amdgcn_sched_barrier(0); \
} while (0)
#define LGK8 do { \
    asm volatile("s_waitcnt lgkmcnt(8)" ::: "memory"); \
    __builtin_amdgcn_sched_barrier(0); \
} while (0)
#define VM0 do { \
    asm volatile("s_waitcnt vmcnt(0)" ::: "memory"); \
    __builtin_amdgcn_sched_barrier(0); \
} while (0)
#define VM4 do { \
    asm volatile("s_waitcnt vmcnt(4)" ::: "memory"); \
    __builtin_amdgcn_sched_barrier(0); \
} while (0)
#define VM6 do { \
    asm volatile("s_waitcnt vmcnt(6)" ::: "memory"); \
    __builtin_amdgcn_sched_barrier(0); \
} while (0)

// ---------------- prep kernels ----------------
__global__ __launch_bounds__(256) void convert_x_kernel(
    const float* __restrict__ x, unsigned short* __restrict__ o) {
    size_t i = (size_t)blockIdx.x * 256 + threadIdx.x;   // 1M float4s
    float4 v = reinterpret_cast<const float4*>(x)[i];
    ushort4 u;
    u.x = f2bf_bits(v.x); u.y = f2bf_bits(v.y);
    u.z = f2bf_bits(v.z); u.w = f2bf_bits(v.w);
    reinterpret_cast<ushort4*>(o)[i] = u;
}

// W [k][n] f32 -> WT [n][k] bf16 (tiled transpose)
__global__ __launch_bounds__(256) void convw_kernel(
    const float* __restrict__ W0, const float* __restrict__ W1,
    const float* __restrict__ W2, const float* __restrict__ W3,
    unsigned short* __restrict__ OT) {
    __shared__ float t[32][33];
    const float* W = (blockIdx.z == 0) ? W0 : (blockIdx.z == 1) ? W1
                    : (blockIdx.z == 2) ? W2 : W3;
    unsigned short* O = OT + (size_t)blockIdx.z * D_ * D_;
    int tx = threadIdx.x & 31, ty = threadIdx.x >> 5;
    int kb = blockIdx.y * 32, nb = blockIdx.x * 32;
#pragma unroll
    for (int i = 0; i < 4; i++)
        t[ty + 8*i][tx] = W[(size_t)(kb + ty + 8*i) * D_ + nb + tx];
    __syncthreads();
#pragma unroll
    for (int i = 0; i < 4; i++) {
        int n = nb + ty + 8*i, k = kb + tx;
        O[(size_t)n * D_ + k] = f2bf_bits(t[tx][ty + 8*i]);
    }
}

// ---------------- QKV GEMM: 256x256 tile, 8 waves, 8-phase (r9) ------------
__global__ __launch_bounds__(512, 2) void gemm_qkv256(
    const unsigned short* __restrict__ A,
    const unsigned short* __restrict__ BT,
    unsigned short* __restrict__ outp)
{
    __shared__ union {
        struct { unsigned short A[2][2][8192]; unsigned short B[2][2][8192]; } s;
        unsigned short vt[256][136];
    } sm;
    const int tid = threadIdx.x, lane = tid & 63, wid = tid >> 6;
    const int lrow = lane & 15, lk8 = lane >> 4, orow = lk8 * 4;
    const int wmo = (wid >> 2) * 64;
    const int wno = (wid & 3) * 32;
    const int m0 = blockIdx.x * 256, n0 = blockIdx.y * 256;

    const int srow = lane >> 3, sgr = lane & 7;
    const unsigned sgo = (unsigned)(wid * 8 + srow) * 1024u
                       + (unsigned)((sgr ^ srow) << 3);
    const unsigned short* Ag = A  + (unsigned)m0 * 1024u + sgo;
    const unsigned short* Bg = BT + (unsigned)n0 * 1024u + sgo;
    const int ldsrb = wid * 512;

    const int sw0 = ((lk8 ^ (lrow & 7)) << 3);
    const int sw1 = (((4 | lk8) ^ (lrow & 7)) << 3);
    int ar[4], br[2];
#pragma unroll
    for (int f = 0; f < 4; f++) ar[f] = (wmo + f * 16 + lrow) * 64;
#pragma unroll
    for (int g = 0; g < 2; g++) br[g] = (wno + g * 16 + lrow) * 64;

    f32x4 acc[8][4] = {};
    bf16x8 af[4][2], bf0[2][2], bf1[2][2];

    auto stA = [&](int par, int mh, unsigned k) {
        unsigned short* d = &sm.s.A[par][mh][ldsrb];
        const unsigned short* g = Ag + (unsigned)mh * 131072u + k;
        gload16(g, d);
        gload16(g + 65536u, d + 4096);
    };
    auto stB = [&](int par, int nh, unsigned k) {
        unsigned short* d = &sm.s.B[par][nh][ldsrb];
        const unsigned short* g = Bg + (unsigned)nh * 131072u + k;
        gload16(g, d);
        gload16(g + 65536u, d + 4096);
    };
    auto lda = [&](int par, int mh) {
        const unsigned short* p = &sm.s.A[par][mh][0];
#pragma unroll
        for (int f = 0; f < 4; f++) {
            af[f][0] = *reinterpret_cast<const bf16x8*>(p + ar[f] + sw0);
            af[f][1] = *reinterpret_cast<const bf16x8*>(p + ar[f] + sw1);
        }
    };
    auto ldb0 = [&](int par, int nh) {
        const unsigned short* p = &sm.s.B[par][nh][0];
#pragma unroll
        for (int g = 0; g < 2; g++) {
            bf0[g][0] = *reinterpret_cast<const bf16x8*>(p + br[g] + sw0);
            bf0[g][1] = *reinterpret_cast<const bf16x8*>(p + br[g] + sw1);
        }
    };
    auto ldb1 = [&](int par, int nh) {
        const unsigned short* p = &sm.s.B[par][nh][0];
#pragma unroll
        for (int g = 0; g < 2; g++) {
            bf1[g][0] = *reinterpret_cast<const bf16x8*>(p + br[g] + sw0);
            bf1[g][1] = *reinterpret_cast<const bf16x8*>(p + br[g] + sw1);
        }
    };
    auto MMA0 = [&](int mh) {
        __builtin_amdgcn_s_setprio(1);
#pragma unroll
        for (int f = 0; f < 4; f++)
#pragma unroll
            for (int g = 0; g < 2; g++)
#pragma unroll
                for (int ks = 0; ks < 2; ks++)
                    acc[mh*4+f][g] = MFMA16(af[f][ks], bf0[g][ks], acc[mh*4+f][g]);
        __builtin_amdgcn_s_setprio(0);
    };
    auto MMA1 = [&](int mh) {
        __builtin_amdgcn_s_setprio(1);
#pragma unroll
        for (int f = 0; f < 4; f++)
#pragma unroll
            for (int g = 0; g < 2; g++)
#pragma unroll
                for (int ks = 0; ks < 2; ks++)
                    acc[mh*4+f][2+g] = MFMA16(af[f][ks], bf1[g][ks], acc[mh*4+f][2+g]);
        __builtin_amdgcn_s_setprio(0);
    };

    stA(0, 0, 0);  stB(0, 0, 0);  stB(0, 1, 0);  stA(0, 1, 0);
    stA(1, 0, 64); stB(1, 0, 64); stB(1, 1, 64);
    VM6; BARR;

#pragma unroll 1
    for (int i = 0; i < 8; i++) {
        const unsigned kA1 = (unsigned)(2*i + 1) * 64u;
        const unsigned k2  = (unsigned)((2*i + 2) & 15) * 64u;
        const unsigned k3  = (unsigned)((2*i + 3) & 15) * 64u;
        lda(0, 0); ldb0(0, 0); stA(1, 1, kA1);
        LGK8; BARR; LGK0; MMA0(0); BARR;
        ldb1(0, 1); stA(0, 0, k2);
        BARR; LGK0; MMA1(0); BARR;
        lda(0, 1); stB(0, 0, k2);
        BARR; LGK0; MMA1(1); BARR;
        stB(0, 1, k2);
        VM6; BARR; MMA0(1); BARR;
        lda(1, 0); ldb0(1, 0); stA(0, 1, k2);
        LGK8; BARR; LGK0; MMA0(0); BARR;
        ldb1(1, 1); stA(1, 0, k3);
        BARR; LGK0; MMA1(0); BARR;
        lda(1, 1); stB(1, 0, k3);
        BARR; LGK0; MMA1(1); BARR;
        stB(1, 1, k3);
        VM6; BARR; MMA0(1); BARR;
    }

    asm volatile("s_waitcnt vmcnt(0)" ::: "memory");
    __builtin_amdgcn_sched_barrier(0);
    __builtin_amdgcn_s_barrier();

    const int which = n0 >> 10;
    const int nl0 = n0 & 1023;
    const int bq = m0 >> 11;
    unsigned short* obase = outp + (size_t)which * 4194304;

    if (which < 2) {
        const float scale = (which == 0) ? (0.125f * LOG2E) : 1.0f;
#pragma unroll
        for (int fi = 0; fi < 8; fi++)
#pragma unroll
            for (int g = 0; g < 4; g++)
#pragma unroll
                for (int r = 0; r < 4; r++) {
                    int m = m0 + (fi >> 2) * 128 + wmo + (fi & 3) * 16 + orow + r;
                    int n = nl0 + (g >> 1) * 128 + wno + (g & 1) * 16 + lrow;
                    int s = m & 2047;
                    obase[(((size_t)(bq * 16 + (n >> 6)) * 2048 + s) << 6) + (n & 63)]
                        = f2bf_bits(acc[fi][g][r] * scale);
                }
    } else {
#pragma unroll
        for (int qm = 0; qm < 2; qm++) {
#pragma unroll
            for (int f = 0; f < 4; f++)
#pragma unroll
                for (int g = 0; g < 4; g++) {
                    const int ml = wmo + f * 16 + orow;
                    const int nc = (g >> 1) * 128 + wno + (g & 1) * 16 + lrow;
                    uint2 w;
                    w.x = cvt_pk_bf16(acc[qm*4+f][g][0], acc[qm*4+f][g][1]);
                    w.y = cvt_pk_bf16(acc[qm*4+f][g][2], acc[qm*4+f][g][3]);
                    *reinterpret_cast<uint2*>(&sm.vt[nc][ml]) = w;
                }
            __syncthreads();
            {
                const int row = tid >> 1, c0 = (tid & 1) * 64;
                unsigned short* dst = obase +
                    ((size_t)(bq * 1024) + nl0 + row) * 2048 +
                    (m0 & 2047) + qm * 128 + c0;
#pragma unroll
                for (int j = 0; j < 64; j += 8)
                    *reinterpret_cast<bf16x8*>(dst + j) =
                        *reinterpret_cast<const bf16x8*>(&sm.vt[row][c0 + j]);
            }
            __syncthreads();
        }
    }
}

// ---------------- proj GEMM (128x64 tiles — round-9 config) ----------------
template<int BN, int MODE>
__global__ __launch_bounds__(256) void gemm_gl(
    const unsigned short* __restrict__ A,
    const unsigned short* __restrict__ BT,
    void* __restrict__ outp,
    const float* __restrict__ bias)
{
    constexpr int K = 1024;
    constexpr int NF = (BN == 128) ? 4 : 2;
    __shared__ struct { unsigned short As[128][64]; unsigned short Bs[BN][64]; } sm;
    const int m0 = blockIdx.x * 128;
    const int n0 = blockIdx.y * BN;
    const int tid = threadIdx.x, lane = tid & 63, wid = tid >> 6;
    const int wm = (wid >> 1) * 64;
    const int wn = (wid & 1) * (BN / 2);
    const int lrow = lane & 15, lk8 = lane >> 4, orow = lk8 * 4;
    f32x4 acc[4][NF] = {};

    for (int k0 = 0; k0 < K; k0 += 64) {
#pragma unroll
        for (int i = 0; i < 4; i++) {
            const int rbase = wid * 32 + i * 8;
            const int rl = rbase + (lane >> 3);
            const int sc = ((lane & 7) ^ (rl & 7)) << 3;
            gload16(A + (size_t)(m0 + rl) * K + k0 + sc, &sm.As[rbase][0]);
        }
#pragma unroll
        for (int i = 0; i < BN / 32; i++) {
            const int rbase = wid * (BN / 4) + i * 8;
            const int rl = rbase + (lane >> 3);
            const int sc = ((lane & 7) ^ (rl & 7)) << 3;
            gload16(BT + (size_t)(n0 + rl) * K + k0 + sc, &sm.Bs[rbase][0]);
        }
        __syncthreads();
#pragma unroll
        for (int ks = 0; ks < 2; ks++) {
            bf16x8 af[4], bfr[NF];
#pragma unroll
            for (int f = 0; f < 4; f++) {
                const int row = wm + f * 16 + lrow;
                const int p = (ks * 4 + lk8) ^ (row & 7);
                af[f] = *reinterpret_cast<const bf16x8*>(&sm.As[row][p * 8]);
            }
#pragma unroll
            for (int f = 0; f < NF; f++) {
                const int row = wn + f * 16 + lrow;
                const int p = (ks * 4 + lk8) ^ (row & 7);
                bfr[f] = *reinterpret_cast<const bf16x8*>(&sm.Bs[row][p * 8]);
            }
            __builtin_amdgcn_s_setprio(1);
#pragma unroll
            for (int mf = 0; mf < 4; mf++)
#pragma unroll
                for (int nf = 0; nf < NF; nf++)
                    acc[mf][nf] = MFMA16(af[mf], bfr[nf], acc[mf][nf]);
            __builtin_amdgcn_s_setprio(0);
        }
        __syncthreads();
    }

    float* o = (float*)outp;
#pragma unroll
    for (int mf = 0; mf < 4; mf++)
#pragma unroll
        for (int nf = 0; nf < NF; nf++)
#pragma unroll
            for (int r = 0; r < 4; r++) {
                int m = m0 + wm + mf*16 + orow + r;
                int n = n0 + wn + nf*16 + lrow;
                o[(size_t)m * 1024 + n] = acc[mf][nf][r] + bias[n];
            }
}

// ---------------- flash attention: r15 datapath + sequential pairing -------
// 512 blocks = 16 pairs x 32 bh, XCD-swizzled. Block p does qt=p then
// qt=31-p: exactly 33 kv-iterations per block (perfect balance, no tail),
// all blocks co-resident at 2/CU. Per-half: 3 rotating K/V buffers with
// counted vmcnt publish (T4); in-register P via cvt_pk + permlane swaps.
__global__ __launch_bounds__(256, 2) void attn_kernel(
    const unsigned short* __restrict__ Q,   // [bh][s][64]
    const unsigned short* __restrict__ Kb,  // [bh][s][64]
    const unsigned short* __restrict__ VT,  // [bh][64][s]
    unsigned short* __restrict__ ctx)       // [b][s][h*64+hd]
{
    __shared__ unsigned short Ks[3][64][64];
    __shared__ unsigned short Vs[3][64][64];
    const int fid = blockIdx.x;                   // 512
    const int xcd = fid & 7, t = fid >> 3;        // 0..63
    const int bh = xcd | ((t & 3) << 3);          // 4 bh per XCD
    const int jp = t >> 2;                        // 0..15
    const int lane = threadIdx.x & 63, wid = threadIdx.x >> 6;
    const int lrow = lane & 15, lk8 = lane >> 4, orow = lk8 * 4;
    const unsigned short* Qp = Q  + (size_t)bh * (S_ * 64);
    const unsigned short* Kp = Kb + (size_t)bh * (S_ * 64);
    const unsigned short* Vp = VT + (size_t)bh * (64 * S_);
    const int b = bh >> 4, h = bh & 15;

    auto stage = [&](int buf, int kv0) {
#pragma unroll
        for (int i = 0; i < 2; i++) {
            const int rbase = wid * 16 + 8 * i;          // wave-uniform
            const int rl = rbase + (lane >> 3);          // per-lane row
            const int sc = (((lane & 7) ^ (rl & 7)) << 3);
            gload16(Kp + (size_t)(kv0 + rl) * 64 + sc, &Ks[buf][rbase][0]);
            gload16(Vp + (size_t)rl * S_ + kv0 + sc, &Vs[buf][rbase][0]);
        }
    };

#pragma unroll 1
    for (int half = 0; half < 2; half++) {
        const int qt = half ? (31 - jp) : jp;
        const int nb = qt + 1;
        const int q0 = qt * 64 + wid * 16;

        if (half) BARR;   // protect K/V buffers from previous half's readers

        stage(0, 0);
        stage(1, 64);     // rows always in-bounds (S=2048); unused if nb<2

        bf16x8 qf[2];
#pragma unroll
        for (int kt = 0; kt < 2; kt++)
            qf[kt] = *reinterpret_cast<const bf16x8*>(
                Qp + (size_t)(q0 + lrow) * 64 + kt*32 + lk8*8);

        f32x4 acc[4] = {};
        float lr = 0.f;

        VM4;    // stage(0) landed; stage(1) still in flight
        BARR;

        int cur = 0, n2 = 2;
#pragma unroll 1
        for (int kvb = 0; kvb < nb; kvb++) {
            if (kvb + 2 < nb) stage(n2, (kvb + 2) * 64);

            // ---- S^T = K·Q^T from swizzled LDS: regs = kv, lane&15 = q ----
            f32x4 sacc[4] = {};
            __builtin_amdgcn_s_setprio(1);
#pragma unroll
            for (int kt = 0; kt < 2; kt++)
#pragma unroll
                for (int nf = 0; nf < 4; nf++) {
                    const int row = nf * 16 + lrow;      // kv row
                    const int g = ((kt << 2) | lk8) ^ (row & 7);
                    bf16x8 kf = *reinterpret_cast<const bf16x8*>(&Ks[cur][row][g << 3]);
                    sacc[nf] = MFMA16(kf, qf[kt], sacc[nf]);
                }
            __builtin_amdgcn_s_setprio(0);
            if (kvb == qt) {   // diagonal: mask kv_local > q_local
#pragma unroll
                for (int nf = 0; nf < 4; nf++)
#pragma unroll
                    for (int r = 0; r < 4; r++)
                        if (nf*16 + orow + r > wid*16 + lrow) sacc[nf][r] = -INFF;
            }
            // ---- fixed-max softmax: p = exp2(s') (log2e pre-folded) ----
            float ps[4];
#pragma unroll
            for (int nf = 0; nf < 4; nf++) {
#pragma unroll
                for (int r = 0; r < 4; r++)
                    sacc[nf][r] = EXP2F(sacc[nf][r]);
                ps[nf] = (sacc[nf][0] + sacc[nf][1]) + (sacc[nf][2] + sacc[nf][3]);
            }
            lr += (ps[0] + ps[1]) + (ps[2] + ps[3]);

            // ---- P -> PV A-frags fully in-register (cvt_pk + swaps) ----
            bf16x8 pf[2];
#pragma unroll
            for (int kt = 0; kt < 2; kt++) {
                unsigned a0 = cvt_pk_bf16(sacc[2*kt][0],   sacc[2*kt][1]);
                unsigned a1 = cvt_pk_bf16(sacc[2*kt][2],   sacc[2*kt][3]);
                unsigned b0 = cvt_pk_bf16(sacc[2*kt+1][0], sacc[2*kt+1][1]);
                unsigned b1 = cvt_pk_bf16(sacc[2*kt+1][2], sacc[2*kt+1][3]);
                asm("v_permlane32_swap_b32 %0, %1" : "+v"(a0), "+v"(b0));
                asm("v_permlane16_swap_b32 %0, %1" : "+v"(a0), "+v"(b0));
                asm("v_permlane32_swap_b32 %0, %1" : "+v"(a1), "+v"(b1));
                asm("v_permlane16_swap_b32 %0, %1" : "+v"(a1), "+v"(b1));
                union { unsigned u[4]; bf16x8 v; } pk;
                pk.u[0] = a0; pk.u[1] = a1; pk.u[2] = b0; pk.u[3] = b1;
                pf[kt] = pk.v;
            }

            __builtin_amdgcn_s_setprio(1);
#pragma unroll
            for (int kt = 0; kt < 2; kt++)
#pragma unroll
                for (int nf = 0; nf < 4; nf++) {
                    const int row = nf * 16 + lrow;      // hd row of VT
                    const int g = ((kt << 2) | lk8) ^ (row & 7);
                    bf16x8 vf = *reinterpret_cast<const bf16x8*>(&Vs[cur][row][g << 3]);
                    acc[nf] = MFMA16(pf[kt], vf, acc[nf]);
                }
            __builtin_amdgcn_s_setprio(0);

            // ---- counted publish: keep newest stage in flight (T4) ----
            if (kvb + 1 < nb) {
                if (kvb + 2 < nb) { VM4; } else { VM0; }
                BARR;
            }
            cur = (cur == 2) ? 0 : cur + 1;
            n2  = (n2  == 2) ? 0 : n2  + 1;
        }

        // drain remaining prefetch before buffer reuse / next half
        asm volatile("s_waitcnt vmcnt(0)" ::: "memory");

        // ---- epilogue: denominator reduce across lk8 groups, write ctx ----
        lr += __shfl_xor(lr, 16);
        lr += __shfl_xor(lr, 32);
        const float inv = 1.0f / lr;      // all lanes: denom for q = lrow
#pragma unroll
        for (int r = 0; r < 4; r++) {
            const float linv = __shfl(inv, (lane & 48) + orow + r);
#pragma unroll
            for (int nf = 0; nf < 4; nf++) {
                int s = q0 + orow + r;
                int col = h * 64 + nf * 16 + lrow;
                ctx[((size_t)(b * S_ + s)) * D_ + col] = f2bf_bits(acc[nf][r] * linv);
            }
        }
    }
}

// ---------------- launch ----------------
extern "C" void kernel_launch(void* const* d_in, const int* in_sizes, int n_in,
                              void* d_out, int out_size, void* d_ws, size_t ws_size,
                              hipStream_t stream) {
    const float* x  = (const float*)d_in[0];
    const float* Wq = (const float*)d_in[1];
    const float* Wk = (const float*)d_in[2];
    const float* Wv = (const float*)d_in[3];
    const float* Wo = (const float*)d_in[4];
    const float* bo = (const float*)d_in[5];
    float* out = (float*)d_out;

    char* ws = (char*)d_ws;
    unsigned short* xb  = (unsigned short*)(ws);                 // 8 MiB
    unsigned short* WT  = (unsigned short*)(ws + 8388608);       // 4 x 2 MiB
    unsigned short* QKV = (unsigned short*)(ws + 16777216);      // 24 MiB: Q,K,VT
    unsigned short* ctx = (unsigned short*)(ws + 41943040);      // 8 MiB

    unsigned short* Qb  = QKV;
    unsigned short* Kb  = QKV + 4194304;
    unsigned short* VTb = QKV + 8388608;

    convert_x_kernel<<<dim3(4096), dim3(256), 0, stream>>>(x, xb);
    convw_kernel<<<dim3(32, 32, 4), dim3(256), 0, stream>>>(Wq, Wk, Wv, Wo, WT);

    // fused QKV projection: 256x256 tiles, N=3072
    gemm_qkv256<<<dim3(16, 12), dim3(512), 0, stream>>>(xb, WT, QKV);

    attn_kernel<<<dim3(512), dim3(256), 0, stream>>>(Qb, Kb, VTb, ctx);

    // output projection: N=1024, 128x64 tiles for 512 blocks
    gemm_gl<64, 1><<<dim3(32, 16), dim3(256), 0, stream>>>(
        ctx, WT + 3145728, (void*)out, bo);
}